// Round 1
// baseline (27002.875 us; speedup 1.0000x reference)
//
#include <hip/hip_runtime.h>
#include <stdint.h>

#define NN 30000
#define NE 480000
#define HID 128
#define NG 128
#define NC 6
#define BN_EPS 1e-5f
#define MROUNDS 48

typedef unsigned int u32;
typedef unsigned long long u64;

__device__ __forceinline__ u32 enc_f32(float f) {
  u32 b = __float_as_uint(f);
  return (b & 0x80000000u) ? ~b : (b | 0x80000000u);
}
__device__ __forceinline__ float dec_f32(u32 u) {
  u32 b = (u & 0x80000000u) ? (u & 0x7FFFFFFFu) : ~u;
  return __uint_as_float(b);
}

// ---------------- init ----------------
__global__ void k_init(const int* __restrict__ ei, int* srcA, int* dstA, int* nvb, int* scal) {
  int t = blockIdx.x * 256 + threadIdx.x;
  if (t < NE) { srcA[t] = ei[t]; dstA[t] = ei[NE + t]; }
  if (t < NN) nvb[t] = 1;
  if (t == 0) scal[0] = NE;  // E_cur
}

__global__ void k_count_valid(const int* __restrict__ nvb, int* cnt) {
  int n = blockIdx.x * 256 + threadIdx.x;
  if (n < NN && nvb[n]) atomicAdd(cnt, 1);
}

// ---------------- SAGE ----------------
__global__ void k_seg_sum_edges(const int* __restrict__ pE, const int* __restrict__ src,
                                const int* __restrict__ dst, const float* __restrict__ x,
                                float* __restrict__ s, float* __restrict__ deg) {
  int E = *pE;
  int t = blockIdx.x * 256 + threadIdx.x;
  int e = t >> 2;
  if (e >= E) return;
  int sub = t & 3;
  int sr = src[e], ds = dst[e];
  const float* xin = x + (size_t)sr * HID + sub * 32;
  float* so = s + (size_t)ds * HID + sub * 32;
#pragma unroll
  for (int i = 0; i < 8; i++) {
    float4 v = *(const float4*)(xin + i * 4);
    atomicAdd(so + i * 4 + 0, v.x); atomicAdd(so + i * 4 + 1, v.y);
    atomicAdd(so + i * 4 + 2, v.z); atomicAdd(so + i * 4 + 3, v.w);
  }
  if (sub == 0) atomicAdd(deg + ds, 1.0f);
}

__global__ void k_mean(float* __restrict__ s, const float* __restrict__ deg) {
  int t = blockIdx.x * 256 + threadIdx.x;
  if (t >= NN * HID) return;
  s[t] /= fmaxf(deg[t >> 7], 1.0f);
}

// out[n][j] = sum_k A1[n][k]*W1[j*ldw+k] + sum_k A2[n][k]*W2[j*ldw+k] + bias[j]; optional relu
__global__ __launch_bounds__(256) void gemm_dual(
    const float* __restrict__ A1, const float* __restrict__ W1,
    const float* __restrict__ A2, const float* __restrict__ W2,
    const float* __restrict__ bias, float* __restrict__ out,
    int M, int ldw, int relu) {
  __shared__ float As[64][33];
  __shared__ float Ws[32][132];  // transposed: Ws[kk][j]
  int row0 = blockIdx.x * 64;
  int tid = threadIdx.x;
  int cid = tid & 31;
  int rid = tid >> 5;
  float acc[8][4];
#pragma unroll
  for (int r = 0; r < 8; r++)
#pragma unroll
    for (int c = 0; c < 4; c++) acc[r][c] = 0.f;

  for (int srcI = 0; srcI < 2; ++srcI) {
    const float* A = srcI ? A2 : A1;
    const float* W = srcI ? W2 : W1;
    for (int kc = 0; kc < 128; kc += 32) {
#pragma unroll
      for (int i = 0; i < 2; ++i) {
        int idx = tid + i * 256;
        int r = idx >> 3;
        int c4 = (idx & 7) << 2;
        int gr = row0 + r;
        float4 v = make_float4(0.f, 0.f, 0.f, 0.f);
        if (gr < M) v = *(const float4*)(A + (size_t)gr * 128 + kc + c4);
        As[r][c4 + 0] = v.x; As[r][c4 + 1] = v.y; As[r][c4 + 2] = v.z; As[r][c4 + 3] = v.w;
      }
#pragma unroll
      for (int i = 0; i < 4; ++i) {
        int idx = tid + i * 256;
        int j = idx >> 3;
        int c4 = (idx & 7) << 2;
        float4 v = *(const float4*)(W + (size_t)j * ldw + kc + c4);
        Ws[c4 + 0][j] = v.x; Ws[c4 + 1][j] = v.y; Ws[c4 + 2][j] = v.z; Ws[c4 + 3][j] = v.w;
      }
      __syncthreads();
#pragma unroll
      for (int kk = 0; kk < 32; ++kk) {
        float4 w = *(const float4*)(&Ws[kk][cid * 4]);
#pragma unroll
        for (int r = 0; r < 8; ++r) {
          float a = As[rid * 8 + r][kk];
          acc[r][0] += a * w.x; acc[r][1] += a * w.y; acc[r][2] += a * w.z; acc[r][3] += a * w.w;
        }
      }
      __syncthreads();
    }
  }
#pragma unroll
  for (int r = 0; r < 8; ++r) {
    int gr = row0 + rid * 8 + r;
    if (gr >= M) continue;
#pragma unroll
    for (int c = 0; c < 4; ++c) {
      float v = acc[r][c] + bias[cid * 4 + c];
      if (relu) v = fmaxf(v, 0.f);
      out[(size_t)gr * 128 + cid * 4 + c] = v;
    }
  }
}

__global__ __launch_bounds__(128) void k_bn_stats(const float* __restrict__ x,
                                                  const int* __restrict__ nvb,
                                                  double* __restrict__ sums) {
  int k = threadIdx.x;
  int n0 = blockIdx.x * 128;
  float s = 0.f, q = 0.f;
  for (int r = 0; r < 128; r++) {
    int n = n0 + r;
    if (n >= NN) break;
    if (!nvb[n]) continue;
    float v = x[(size_t)n * HID + k];
    s += v; q += v * v;
  }
  atomicAdd(&sums[k], (double)s);
  atomicAdd(&sums[HID + k], (double)q);
}

__global__ void k_bn_apply(float* __restrict__ x, const double* __restrict__ sums,
                           const int* __restrict__ cnt, const float* __restrict__ gamma,
                           const float* __restrict__ beta) {
  int t = blockIdx.x * 256 + threadIdx.x;
  if (t >= NN * HID) return;
  int k = t & 127;
  double c = (double)((*cnt > 1) ? *cnt : 1);
  double mu = sums[k] / c;
  double var = sums[HID + k] / c - mu * mu;
  if (var < 0.0) var = 0.0;
  float inv = (float)(1.0 / sqrt(var + (double)BN_EPS));
  x[t] = gamma[k] * (x[t] - (float)mu) * inv + beta[k];
}

// ---------------- edge pool ----------------
__global__ void k_node_proj(const float* __restrict__ x, const float* __restrict__ Wp,
                            float* __restrict__ px1, float* __restrict__ px2) {
  int n = blockIdx.x * 256 + threadIdx.x;
  if (n >= NN) return;
  const float* xr = x + (size_t)n * HID;
  float s1 = 0.f, s2 = 0.f;
#pragma unroll 8
  for (int k = 0; k < HID; k += 4) {
    float4 v = *(const float4*)(xr + k);
    float4 w1 = *(const float4*)(Wp + k);
    float4 w2 = *(const float4*)(Wp + HID + k);
    s1 += v.x * w1.x + v.y * w1.y + v.z * w1.z + v.w * w1.w;
    s2 += v.x * w2.x + v.y * w2.y + v.z * w2.z + v.w * w2.w;
  }
  px1[n] = s1; px2[n] = s2;
}

__global__ void k_pool_init(const int* __restrict__ nvb, int* matched, int* cluster,
                            int* chosen, int* progress, u64* top, u32* nmx, double* den) {
  int t = blockIdx.x * 256 + threadIdx.x;
  if (t < NN) {
    matched[t] = nvb[t] ? 0 : 1;
    cluster[t] = t;
    chosen[t] = -1;
    top[t] = 0ull;
    nmx[t] = 0u;
    den[t] = 0.0;
  }
  if (t < MROUNDS) progress[t] = 0;
}

__global__ void k_raw_max(const int* __restrict__ pE, const int* __restrict__ src,
                          const int* __restrict__ dst, const float* __restrict__ px1,
                          const float* __restrict__ px2, const float* __restrict__ bp,
                          float* __restrict__ raw, u32* __restrict__ nmx) {
  int e = blockIdx.x * 256 + threadIdx.x;
  if (e >= *pE) return;
  float r = px1[src[e]] + px2[dst[e]] + *bp;
  raw[e] = r;
  atomicMax(&nmx[dst[e]], enc_f32(r));
}

__global__ void k_z_den(const int* __restrict__ pE, const int* __restrict__ dst,
                        float* __restrict__ raw, const u32* __restrict__ nmx,
                        double* __restrict__ den) {
  int e = blockIdx.x * 256 + threadIdx.x;
  if (e >= *pE) return;
  float m = dec_f32(nmx[dst[e]]);
  float z = expf(raw[e] - m);
  raw[e] = z;
  atomicAdd(&den[dst[e]], (double)z);
}

__global__ void k_score(const int* __restrict__ pE, const int* __restrict__ src,
                        const int* __restrict__ dst, const float* __restrict__ z,
                        const double* __restrict__ den, float* __restrict__ score,
                        int* __restrict__ active) {
  int e = blockIdx.x * 256 + threadIdx.x;
  if (e >= *pE) return;
  double d = den[dst[e]];
  if (d < 1e-16) d = 1e-16;
  score[e] = (float)((double)z[e] / d) + 0.5f;
  active[e] = (src[e] != dst[e]) ? 1 : 0;
}

__device__ __forceinline__ u64 make_key(int r, float sc, int e) {
  return ((u64)(r + 1) << 51) | ((u64)__float_as_uint(sc) << 19) | (u64)(0x7FFFFu - (u32)e);
}

__global__ void k_match_a(int r, const int* __restrict__ pE, const int* __restrict__ src,
                          const int* __restrict__ dst, const float* __restrict__ score,
                          int* __restrict__ active, const int* __restrict__ matched,
                          u64* __restrict__ top, int* __restrict__ progress) {
  if (r > 0 && progress[r - 1] == 0) return;
  int E = *pE;
  int any = 0;
  for (int e = blockIdx.x * blockDim.x + threadIdx.x; e < E; e += gridDim.x * blockDim.x) {
    if (!active[e]) continue;
    int s = src[e], d = dst[e];
    if (matched[s] | matched[d]) { active[e] = 0; continue; }
    u64 key = make_key(r, score[e], e);
    atomicMax(&top[s], key);
    atomicMax(&top[d], key);
    any = 1;
  }
  if (any) progress[r] = 1;
}

__global__ void k_match_b(int r, const int* __restrict__ pE, const int* __restrict__ src,
                          const int* __restrict__ dst, const float* __restrict__ score,
                          int* __restrict__ active, int* __restrict__ matched,
                          int* __restrict__ cluster, int* __restrict__ chosen,
                          const u64* __restrict__ top, const int* __restrict__ progress) {
  if (progress[r] == 0) return;
  int E = *pE;
  for (int e = blockIdx.x * blockDim.x + threadIdx.x; e < E; e += gridDim.x * blockDim.x) {
    if (!active[e]) continue;
    int s = src[e], d = dst[e];
    u64 key = make_key(r, score[e], e);
    if (top[s] == key && top[d] == key) {
      matched[s] = 1; matched[d] = 1;
      int rep = s < d ? s : d;
      int oth = s < d ? d : s;
      cluster[oth] = rep;
      chosen[rep] = e;
      active[e] = 0;
    }
  }
}

__global__ void k_nscore(const int* __restrict__ chosen, const float* __restrict__ score,
                         float* __restrict__ nscore) {
  int n = blockIdx.x * 256 + threadIdx.x;
  if (n >= NN) return;
  int c = chosen[n];
  nscore[n] = (c >= 0) ? score[c] : 1.0f;
}

__global__ void k_cluster_sum(const int* __restrict__ cluster, const float* __restrict__ x,
                              float* __restrict__ out) {
  int t = blockIdx.x * 256 + threadIdx.x;
  int n = t >> 2;
  if (n >= NN) return;
  int sub = t & 3;
  int c = cluster[n];
  const float* xr = x + (size_t)n * HID + sub * 32;
  float* o = out + (size_t)c * HID + sub * 32;
#pragma unroll
  for (int i = 0; i < 8; i++) {
    float4 v = *(const float4*)(xr + i * 4);
    atomicAdd(o + i * 4 + 0, v.x); atomicAdd(o + i * 4 + 1, v.y);
    atomicAdd(o + i * 4 + 2, v.z); atomicAdd(o + i * 4 + 3, v.w);
  }
}

__global__ void k_scale_newx(float* __restrict__ x, const float* __restrict__ nscore) {
  int t = blockIdx.x * 256 + threadIdx.x;
  if (t >= NN * HID) return;
  x[t] *= nscore[t >> 7];
}

__global__ void k_nvb_update(int* __restrict__ nvb, const int* __restrict__ cluster) {
  int n = blockIdx.x * 256 + threadIdx.x;
  if (n >= NN) return;
  nvb[n] = (nvb[n] && cluster[n] == n) ? 1 : 0;
}

// ---------------- dedup (sorted unique of (cs,cd)) ----------------
__global__ void k_bucket_count(const int* __restrict__ pE, const int* __restrict__ src,
                               const int* __restrict__ cluster, int* __restrict__ bcount) {
  int e = blockIdx.x * 256 + threadIdx.x;
  if (e >= *pE) return;
  atomicAdd(&bcount[cluster[src[e]]], 1);
}

__global__ __launch_bounds__(1024) void k_scan(const int* __restrict__ in, int* __restrict__ out,
                                               int n, int* totalDst) {
  __shared__ int part[1024];
  int t = threadIdx.x;
  int chunk = (n + 1023) / 1024;
  int b = t * chunk, e = b + chunk;
  if (b > n) b = n;
  if (e > n) e = n;
  int s = 0;
  for (int i = b; i < e; i++) s += in[i];
  part[t] = s;
  __syncthreads();
  for (int off = 1; off < 1024; off <<= 1) {
    int v = (t >= off) ? part[t - off] : 0;
    __syncthreads();
    part[t] += v;
    __syncthreads();
  }
  int excl = (t == 0) ? 0 : part[t - 1];
  int total = part[1023];
  for (int i = b; i < e; i++) { out[i] = excl; excl += in[i]; }
  if (t == 0) {
    out[n] = total;
    if (totalDst) *totalDst = total;
  }
}

__global__ void k_bucket_scatter(const int* __restrict__ pE, const int* __restrict__ src,
                                 const int* __restrict__ dst, const int* __restrict__ cluster,
                                 const int* __restrict__ boffs, int* __restrict__ bcursor,
                                 int* __restrict__ bucket) {
  int e = blockIdx.x * 256 + threadIdx.x;
  if (e >= *pE) return;
  int cs = cluster[src[e]], cd = cluster[dst[e]];
  int pos = boffs[cs] + atomicAdd(&bcursor[cs], 1);
  bucket[pos] = cd;
}

__global__ void k_sort_dedup(const int* __restrict__ boffs, int* __restrict__ bucket,
                             int* __restrict__ ucount) {
  int v = blockIdx.x * 256 + threadIdx.x;
  if (v >= NN) return;
  int b = boffs[v], e = boffs[v + 1];
  for (int i = b + 1; i < e; i++) {
    int key = bucket[i];
    int j = i - 1;
    while (j >= b && bucket[j] > key) { bucket[j + 1] = bucket[j]; j--; }
    bucket[j + 1] = key;
  }
  int u = 0, prev = -2147483648;
  for (int i = b; i < e; i++) {
    int x = bucket[i];
    if (x != prev) { bucket[b + u] = x; u++; prev = x; }
  }
  ucount[v] = u;
}

__global__ void k_emit(const int* __restrict__ boffs, const int* __restrict__ bucket,
                       const int* __restrict__ bucount, const int* __restrict__ bnoffs,
                       int* __restrict__ srcO, int* __restrict__ dstO) {
  int v = blockIdx.x * 256 + threadIdx.x;
  if (v >= NN) return;
  int u = bucount[v], b = boffs[v], o = bnoffs[v];
  for (int i = 0; i < u; i++) { srcO[o + i] = v; dstO[o + i] = bucket[b + i]; }
}

// ---------------- readout ----------------
__global__ void k_graph_pool(const int* __restrict__ nvb, const int* __restrict__ batch,
                             const float* __restrict__ x, float* __restrict__ gsum,
                             float* __restrict__ gcnt) {
  int t = blockIdx.x * 256 + threadIdx.x;
  int n = t >> 2;
  if (n >= NN) return;
  if (!nvb[n]) return;
  int sub = t & 3;
  int g = batch[n];
  const float* xr = x + (size_t)n * HID + sub * 32;
  float* o = gsum + (size_t)g * HID + sub * 32;
#pragma unroll
  for (int i = 0; i < 8; i++) {
    float4 v = *(const float4*)(xr + i * 4);
    atomicAdd(o + i * 4 + 0, v.x); atomicAdd(o + i * 4 + 1, v.y);
    atomicAdd(o + i * 4 + 2, v.z); atomicAdd(o + i * 4 + 3, v.w);
  }
  if (sub == 0) atomicAdd(&gcnt[g], 1.0f);
}

__global__ __launch_bounds__(128) void k_head1(const float* __restrict__ gsum,
                                               const float* __restrict__ gcnt,
                                               const float* __restrict__ Wf1,
                                               const float* __restrict__ bf1,
                                               float* __restrict__ hfc) {
  int g = blockIdx.x;
  int j = threadIdx.x;
  __shared__ float p[HID];
  float c = fmaxf(gcnt[g], 1.f);
  p[j] = gsum[g * HID + j] / c;
  __syncthreads();
  float s = bf1[j];
  const float* w = Wf1 + (size_t)j * HID;
  for (int k = 0; k < HID; k++) s += p[k] * w[k];
  hfc[g * HID + j] = fmaxf(s, 0.f);
}

__global__ void k_head2(const float* __restrict__ hfc, const float* __restrict__ Wf2,
                        const float* __restrict__ bf2, float* __restrict__ out) {
  int g = blockIdx.x;
  int t = threadIdx.x;
  __shared__ float lg[NC];
  if (t < NC) {
    float s = bf2[t];
    const float* w = Wf2 + (size_t)t * HID;
    const float* h = hfc + (size_t)g * HID;
    for (int k = 0; k < HID; k++) s += h[k] * w[k];
    lg[t] = s;
  }
  __syncthreads();
  if (t == 0) {
    float m = lg[0];
    for (int c = 1; c < NC; c++) m = fmaxf(m, lg[c]);
    float se = 0.f;
    for (int c = 0; c < NC; c++) se += expf(lg[c] - m);
    float lse = m + logf(se);
    for (int c = 0; c < NC; c++) out[g * NC + c] = lg[c] - lse;
  }
}

extern "C" void kernel_launch(void* const* d_in, const int* in_sizes, int n_in,
                              void* d_out, int out_size, void* d_ws, size_t ws_size,
                              hipStream_t stream) {
  const float* x0 = (const float*)d_in[0];
  const int* ei = (const int*)d_in[1];
  const int* batch = (const int*)d_in[2];
  const float* Wl = (const float*)d_in[3];
  const float* bl = (const float*)d_in[4];
  const float* Wr = (const float*)d_in[5];
  const float* gamma = (const float*)d_in[6];
  const float* beta = (const float*)d_in[7];
  const float* Wlin = (const float*)d_in[8];
  const float* blin = (const float*)d_in[9];
  const float* Wp = (const float*)d_in[10];
  const float* bp = (const float*)d_in[11];
  const float* Wf1 = (const float*)d_in[12];
  const float* bf1 = (const float*)d_in[13];
  const float* Wf2 = (const float*)d_in[14];
  const float* bf2 = (const float*)d_in[15];
  float* out = (float*)d_out;

  const int NH = NN * HID;
  size_t off = 0;
  char* base = (char*)d_ws;
  auto carve = [&](size_t bytes) -> char* {
    char* p = base + off;
    off += (bytes + 255) & ~(size_t)255;
    return p;
  };
  float* xa = (float*)carve((size_t)NH * 4);
  float* xb = (float*)carve((size_t)NH * 4);
  float* xc = (float*)carve((size_t)NH * 4);
  float* xd = (float*)carve((size_t)NH * 4);
  int* srcA = (int*)carve((size_t)NE * 4);
  int* dstA = (int*)carve((size_t)NE * 4);
  int* srcB = (int*)carve((size_t)NE * 4);
  int* dstB = (int*)carve((size_t)NE * 4);
  float* eraw = (float*)carve((size_t)NE * 4);
  float* escore = (float*)carve((size_t)NE * 4);
  int* eactive = (int*)carve((size_t)NE * 4);
  int* ebucket = (int*)carve((size_t)NE * 4);
  u64* ntop = (u64*)carve((size_t)NN * 8);
  u32* nmx = (u32*)carve((size_t)NN * 4);
  double* nden = (double*)carve((size_t)NN * 8);
  float* npx1 = (float*)carve((size_t)NN * 4);
  float* npx2 = (float*)carve((size_t)NN * 4);
  int* ncluster = (int*)carve((size_t)NN * 4);
  int* nchosen = (int*)carve((size_t)NN * 4);
  int* nmatched = (int*)carve((size_t)NN * 4);
  int* nvb = (int*)carve((size_t)NN * 4);
  float* nscore = (float*)carve((size_t)NN * 4);
  float* degc = (float*)carve((size_t)NN * 4);
  int* b3 = (int*)carve((size_t)3 * NN * 4);
  int* bcount = b3;
  int* bcursor = b3 + NN;
  int* bucount = b3 + 2 * NN;
  int* boffs = (int*)carve((size_t)(NN + 1) * 4);
  int* bnoffs = (int*)carve((size_t)(NN + 1) * 4);
  double* bnsum = (double*)carve((size_t)2 * HID * 8);
  float* gbuf = (float*)carve((size_t)(NG * HID + NG) * 4);
  float* gsum = gbuf;
  float* gcnt = gbuf + NG * HID;
  float* ghfc = (float*)carve((size_t)NG * HID * 4);
  int* scal = (int*)carve(64 * 4);
  int* progress = (int*)carve(MROUNDS * 4);
  (void)ws_size; (void)n_in; (void)in_sizes; (void)out_size;

  int* pE = scal;       // E_cur
  int* pcnt = scal + 1; // valid node count

  hipMemcpyAsync(xa, x0, (size_t)NH * 4, hipMemcpyDeviceToDevice, stream);
  k_init<<<1875, 256, 0, stream>>>(ei, srcA, dstA, nvb, scal);

  int* srcC = srcA; int* dstC = dstA; int* srcN = srcB; int* dstN = dstB;
  float* xcur = xa;
  float* xtmp = xd;

  auto sage = [&](const float* xin, float* xout, int L) {
    hipMemsetAsync(xtmp, 0, (size_t)NH * 4, stream);
    hipMemsetAsync(degc, 0, (size_t)NN * 4, stream);
    k_seg_sum_edges<<<7500, 256, 0, stream>>>(pE, srcC, dstC, xin, xtmp, degc);
    k_mean<<<15000, 256, 0, stream>>>(xtmp, degc);
    gemm_dual<<<469, 256, 0, stream>>>(xtmp, Wl + (size_t)L * HID * HID, xin,
                                       Wr + (size_t)L * HID * HID, bl + (size_t)L * HID,
                                       xout, NN, HID, 1);
    hipMemsetAsync(bnsum, 0, (size_t)2 * HID * 8, stream);
    k_bn_stats<<<235, 128, 0, stream>>>(xout, nvb, bnsum);
    k_bn_apply<<<15000, 256, 0, stream>>>(xout, bnsum, pcnt, gamma + (size_t)L * HID,
                                          beta + (size_t)L * HID);
  };

  for (int b = 0; b < 3; b++) {
    hipMemsetAsync(pcnt, 0, 4, stream);
    k_count_valid<<<118, 256, 0, stream>>>(nvb, pcnt);

    sage(xcur, xb, 2 * b);
    sage(xb, xc, 2 * b + 1);
    gemm_dual<<<469, 256, 0, stream>>>(xc, Wlin + (size_t)b * HID * 2 * HID, xb,
                                       Wlin + (size_t)b * HID * 2 * HID + HID,
                                       blin + (size_t)b * HID, xcur, NN, 2 * HID, 0);

    // ----- edge pooling -----
    k_node_proj<<<118, 256, 0, stream>>>(xcur, Wp + (size_t)b * 2 * HID, npx1, npx2);
    k_pool_init<<<118, 256, 0, stream>>>(nvb, nmatched, ncluster, nchosen, progress, ntop, nmx, nden);
    k_raw_max<<<1875, 256, 0, stream>>>(pE, srcC, dstC, npx1, npx2, bp + b, eraw, nmx);
    k_z_den<<<1875, 256, 0, stream>>>(pE, dstC, eraw, nmx, nden);
    k_score<<<1875, 256, 0, stream>>>(pE, srcC, dstC, eraw, nden, escore, eactive);
    for (int r = 0; r < MROUNDS; r++) {
      k_match_a<<<512, 256, 0, stream>>>(r, pE, srcC, dstC, escore, eactive, nmatched, ntop, progress);
      k_match_b<<<512, 256, 0, stream>>>(r, pE, srcC, dstC, escore, eactive, nmatched, ncluster,
                                         nchosen, ntop, progress);
    }
    k_nscore<<<118, 256, 0, stream>>>(nchosen, escore, nscore);
    hipMemsetAsync(xtmp, 0, (size_t)NH * 4, stream);
    k_cluster_sum<<<469, 256, 0, stream>>>(ncluster, xcur, xtmp);
    k_scale_newx<<<15000, 256, 0, stream>>>(xtmp, nscore);
    k_nvb_update<<<118, 256, 0, stream>>>(nvb, ncluster);

    hipMemsetAsync(b3, 0, (size_t)3 * NN * 4, stream);
    k_bucket_count<<<1875, 256, 0, stream>>>(pE, srcC, ncluster, bcount);
    k_scan<<<1, 1024, 0, stream>>>(bcount, boffs, NN, (int*)nullptr);
    k_bucket_scatter<<<1875, 256, 0, stream>>>(pE, srcC, dstC, ncluster, boffs, bcursor, ebucket);
    k_sort_dedup<<<118, 256, 0, stream>>>(boffs, ebucket, bucount);
    k_scan<<<1, 1024, 0, stream>>>(bucount, bnoffs, NN, pE);
    k_emit<<<118, 256, 0, stream>>>(boffs, ebucket, bucount, bnoffs, srcN, dstN);

    { int* t = srcC; srcC = srcN; srcN = t; t = dstC; dstC = dstN; dstN = t; }
    { float* t = xcur; xcur = xtmp; xtmp = t; }
  }

  hipMemsetAsync(gbuf, 0, (size_t)(NG * HID + NG) * 4, stream);
  k_graph_pool<<<469, 256, 0, stream>>>(nvb, batch, xcur, gsum, gcnt);
  k_head1<<<NG, 128, 0, stream>>>(gsum, gcnt, Wf1, bf1, ghfc);
  k_head2<<<NG, 32, 0, stream>>>(ghfc, Wf2, bf2, out);
}

// Round 2
// 7372.914 us; speedup vs baseline: 3.6624x; 3.6624x over previous
//
#include <hip/hip_runtime.h>
#include <stdint.h>

#define NN 30000
#define NE 480000
#define HID 128
#define NG 128
#define NC 6
#define BN_EPS 1e-5f
#define MROUNDS 48

typedef unsigned int u32;
typedef unsigned long long u64;

// ---------------- init ----------------
__global__ void k_init(const int* __restrict__ ei, int* srcA, int* dstA, int* nvb, int* scal) {
  int t = blockIdx.x * 256 + threadIdx.x;
  if (t < NE) { srcA[t] = ei[t]; dstA[t] = ei[NE + t]; }
  if (t < NN) nvb[t] = 1;
  if (t == 0) scal[0] = NE;  // E_cur
}

__global__ void k_count_valid(const int* __restrict__ nvb, int* cnt) {
  int n = blockIdx.x * 256 + threadIdx.x;
  if (n < NN && nvb[n]) atomicAdd(cnt, 1);
}

// ---------------- CSR build (by dst) ----------------
__global__ void k_deg_count(const int* __restrict__ pE, const int* __restrict__ dst,
                            int* __restrict__ cnt) {
  int e = blockIdx.x * 256 + threadIdx.x;
  if (e >= *pE) return;
  atomicAdd(&cnt[dst[e]], 1);
}

__global__ void k_csr_scatter(const int* __restrict__ pE, const int* __restrict__ dst,
                              const int* __restrict__ coff, int* __restrict__ cursor,
                              int* __restrict__ eids) {
  int e = blockIdx.x * 256 + threadIdx.x;
  if (e >= *pE) return;
  int d = dst[e];
  int pos = coff[d] + atomicAdd(&cursor[d], 1);
  eids[pos] = e;
}

// ---------------- SAGE mean aggregation: CSR gather, 32 lanes/node ----------------
__global__ __launch_bounds__(256) void k_sage_gather(
    const int* __restrict__ coff, const int* __restrict__ eids,
    const int* __restrict__ src, const float* __restrict__ x,
    float* __restrict__ mean) {
  int grp = threadIdx.x >> 5;           // 8 nodes per block
  int lane = threadIdx.x & 31;
  int n = blockIdx.x * 8 + grp;
  if (n >= NN) return;
  int b = coff[n], e2 = coff[n + 1];
  float4 acc = make_float4(0.f, 0.f, 0.f, 0.f);
  for (int i = b; i < e2; i++) {
    int s = src[eids[i]];
    float4 v = *(const float4*)(x + (size_t)s * HID + lane * 4);
    acc.x += v.x; acc.y += v.y; acc.z += v.z; acc.w += v.w;
  }
  float inv = 1.0f / fmaxf((float)(e2 - b), 1.0f);
  acc.x *= inv; acc.y *= inv; acc.z *= inv; acc.w *= inv;
  *(float4*)(mean + (size_t)n * HID + lane * 4) = acc;
}

// out[n][j] = sum_k A1[n][k]*W1[j*ldw+k] + sum_k A2[n][k]*W2[j*ldw+k] + bias[j]; optional relu
__global__ __launch_bounds__(256) void gemm_dual(
    const float* __restrict__ A1, const float* __restrict__ W1,
    const float* __restrict__ A2, const float* __restrict__ W2,
    const float* __restrict__ bias, float* __restrict__ out,
    int M, int ldw, int relu) {
  __shared__ float As[64][33];
  __shared__ float Ws[32][132];  // transposed: Ws[kk][j]
  int row0 = blockIdx.x * 64;
  int tid = threadIdx.x;
  int cid = tid & 31;
  int rid = tid >> 5;
  float acc[8][4];
#pragma unroll
  for (int r = 0; r < 8; r++)
#pragma unroll
    for (int c = 0; c < 4; c++) acc[r][c] = 0.f;

  for (int srcI = 0; srcI < 2; ++srcI) {
    const float* A = srcI ? A2 : A1;
    const float* W = srcI ? W2 : W1;
    for (int kc = 0; kc < 128; kc += 32) {
#pragma unroll
      for (int i = 0; i < 2; ++i) {
        int idx = tid + i * 256;
        int r = idx >> 3;
        int c4 = (idx & 7) << 2;
        int gr = row0 + r;
        float4 v = make_float4(0.f, 0.f, 0.f, 0.f);
        if (gr < M) v = *(const float4*)(A + (size_t)gr * 128 + kc + c4);
        As[r][c4 + 0] = v.x; As[r][c4 + 1] = v.y; As[r][c4 + 2] = v.z; As[r][c4 + 3] = v.w;
      }
#pragma unroll
      for (int i = 0; i < 4; ++i) {
        int idx = tid + i * 256;
        int j = idx >> 3;
        int c4 = (idx & 7) << 2;
        float4 v = *(const float4*)(W + (size_t)j * ldw + kc + c4);
        Ws[c4 + 0][j] = v.x; Ws[c4 + 1][j] = v.y; Ws[c4 + 2][j] = v.z; Ws[c4 + 3][j] = v.w;
      }
      __syncthreads();
#pragma unroll
      for (int kk = 0; kk < 32; ++kk) {
        float4 w = *(const float4*)(&Ws[kk][cid * 4]);
#pragma unroll
        for (int r = 0; r < 8; ++r) {
          float a = As[rid * 8 + r][kk];
          acc[r][0] += a * w.x; acc[r][1] += a * w.y; acc[r][2] += a * w.z; acc[r][3] += a * w.w;
        }
      }
      __syncthreads();
    }
  }
#pragma unroll
  for (int r = 0; r < 8; ++r) {
    int gr = row0 + rid * 8 + r;
    if (gr >= M) continue;
#pragma unroll
    for (int c = 0; c < 4; ++c) {
      float v = acc[r][c] + bias[cid * 4 + c];
      if (relu) v = fmaxf(v, 0.f);
      out[(size_t)gr * 128 + cid * 4 + c] = v;
    }
  }
}

__global__ __launch_bounds__(128) void k_bn_stats(const float* __restrict__ x,
                                                  const int* __restrict__ nvb,
                                                  double* __restrict__ sums) {
  int k = threadIdx.x;
  int n0 = blockIdx.x * 128;
  float s = 0.f, q = 0.f;
  for (int r = 0; r < 128; r++) {
    int n = n0 + r;
    if (n >= NN) break;
    if (!nvb[n]) continue;
    float v = x[(size_t)n * HID + k];
    s += v; q += v * v;
  }
  atomicAdd(&sums[k], (double)s);
  atomicAdd(&sums[HID + k], (double)q);
}

__global__ void k_bn_apply(float* __restrict__ x, const double* __restrict__ sums,
                           const int* __restrict__ cnt, const float* __restrict__ gamma,
                           const float* __restrict__ beta) {
  int t = blockIdx.x * 256 + threadIdx.x;
  if (t >= NN * HID) return;
  int k = t & 127;
  double c = (double)((*cnt > 1) ? *cnt : 1);
  double mu = sums[k] / c;
  double var = sums[HID + k] / c - mu * mu;
  if (var < 0.0) var = 0.0;
  float inv = (float)(1.0 / sqrt(var + (double)BN_EPS));
  x[t] = gamma[k] * (x[t] - (float)mu) * inv + beta[k];
}

// ---------------- edge pool ----------------
__global__ void k_node_proj(const float* __restrict__ x, const float* __restrict__ Wp,
                            float* __restrict__ px1, float* __restrict__ px2) {
  int n = blockIdx.x * 256 + threadIdx.x;
  if (n >= NN) return;
  const float* xr = x + (size_t)n * HID;
  float s1 = 0.f, s2 = 0.f;
#pragma unroll 8
  for (int k = 0; k < HID; k += 4) {
    float4 v = *(const float4*)(xr + k);
    float4 w1 = *(const float4*)(Wp + k);
    float4 w2 = *(const float4*)(Wp + HID + k);
    s1 += v.x * w1.x + v.y * w1.y + v.z * w1.z + v.w * w1.w;
    s2 += v.x * w2.x + v.y * w2.y + v.z * w2.z + v.w * w2.w;
  }
  px1[n] = s1; px2[n] = s2;
}

__global__ void k_pool_init(const int* __restrict__ nvb, int* matched, int* cluster,
                            int* chosen, int* progress, u64* top) {
  int t = blockIdx.x * 256 + threadIdx.x;
  if (t < NN) {
    matched[t] = nvb[t] ? 0 : 1;
    cluster[t] = t;
    chosen[t] = -1;
    top[t] = 0ull;
  }
  if (t < MROUNDS) progress[t] = 0;
}

// per-dst softmax over CSR: thread per node
__global__ void k_edge_softmax(const int* __restrict__ coff, const int* __restrict__ eids,
                               const int* __restrict__ src, const float* __restrict__ px1,
                               const float* __restrict__ px2, const float* __restrict__ bp,
                               float* __restrict__ score, int* __restrict__ active) {
  int n = blockIdx.x * 256 + threadIdx.x;
  if (n >= NN) return;
  int b = coff[n], e2 = coff[n + 1];
  if (b == e2) return;
  float p2 = px2[n] + *bp;
  float mx = -3.4e38f;
  for (int i = b; i < e2; i++) {
    float r = px1[src[eids[i]]] + p2;
    mx = fmaxf(mx, r);
  }
  double den = 0.0;
  for (int i = b; i < e2; i++) {
    int eid = eids[i];
    float z = expf(px1[src[eid]] + p2 - mx);
    score[eid] = z;
    den += (double)z;
  }
  if (den < 1e-16) den = 1e-16;
  double invd = 1.0 / den;
  for (int i = b; i < e2; i++) {
    int eid = eids[i];
    score[eid] = (float)((double)score[eid] * invd) + 0.5f;
    active[eid] = (src[eid] != n) ? 1 : 0;
  }
}

__device__ __forceinline__ u64 make_key(int r, float sc, int e) {
  return ((u64)(r + 1) << 51) | ((u64)__float_as_uint(sc) << 19) | (u64)(0x7FFFFu - (u32)e);
}

__global__ void k_match_a(int r, const int* __restrict__ pE, const int* __restrict__ src,
                          const int* __restrict__ dst, const float* __restrict__ score,
                          int* __restrict__ active, const int* __restrict__ matched,
                          u64* __restrict__ top, int* __restrict__ progress) {
  if (r > 0 && progress[r - 1] == 0) return;
  int E = *pE;
  int any = 0;
  for (int e = blockIdx.x * blockDim.x + threadIdx.x; e < E; e += gridDim.x * blockDim.x) {
    if (!active[e]) continue;
    int s = src[e], d = dst[e];
    if (matched[s] | matched[d]) { active[e] = 0; continue; }
    u64 key = make_key(r, score[e], e);
    atomicMax(&top[s], key);
    atomicMax(&top[d], key);
    any = 1;
  }
  if (any) progress[r] = 1;
}

__global__ void k_match_b(int r, const int* __restrict__ pE, const int* __restrict__ src,
                          const int* __restrict__ dst, const float* __restrict__ score,
                          int* __restrict__ active, int* __restrict__ matched,
                          int* __restrict__ cluster, int* __restrict__ chosen,
                          const u64* __restrict__ top, const int* __restrict__ progress) {
  if (progress[r] == 0) return;
  int E = *pE;
  for (int e = blockIdx.x * blockDim.x + threadIdx.x; e < E; e += gridDim.x * blockDim.x) {
    if (!active[e]) continue;
    int s = src[e], d = dst[e];
    u64 key = make_key(r, score[e], e);
    if (top[s] == key && top[d] == key) {
      matched[s] = 1; matched[d] = 1;
      int rep = s < d ? s : d;
      int oth = s < d ? d : s;
      cluster[oth] = rep;
      chosen[rep] = e;
      active[e] = 0;
    }
  }
}

// new_x gather: clusters have at most 2 members (pairwise matching)
__global__ __launch_bounds__(256) void k_new_x(
    const int* __restrict__ cluster, const int* __restrict__ chosen,
    const int* __restrict__ src, const int* __restrict__ dst,
    const float* __restrict__ score, const float* __restrict__ x,
    float* __restrict__ out) {
  int grp = threadIdx.x >> 5;
  int lane = threadIdx.x & 31;
  int n = blockIdx.x * 8 + grp;
  if (n >= NN) return;
  float4 v = make_float4(0.f, 0.f, 0.f, 0.f);
  if (cluster[n] == n) {
    v = *(const float4*)(x + (size_t)n * HID + lane * 4);
    int ch = chosen[n];
    if (ch >= 0) {
      int s = src[ch], d = dst[ch];
      int partner = (s == n) ? d : s;
      float4 w = *(const float4*)(x + (size_t)partner * HID + lane * 4);
      float sc = score[ch];
      v.x = (v.x + w.x) * sc; v.y = (v.y + w.y) * sc;
      v.z = (v.z + w.z) * sc; v.w = (v.w + w.w) * sc;
    }
  }
  *(float4*)(out + (size_t)n * HID + lane * 4) = v;
}

__global__ void k_nvb_update(int* __restrict__ nvb, const int* __restrict__ cluster) {
  int n = blockIdx.x * 256 + threadIdx.x;
  if (n >= NN) return;
  nvb[n] = (nvb[n] && cluster[n] == n) ? 1 : 0;
}

// ---------------- dedup (sorted unique of (cs,cd)) ----------------
__global__ void k_bucket_count(const int* __restrict__ pE, const int* __restrict__ src,
                               const int* __restrict__ cluster, int* __restrict__ bcount) {
  int e = blockIdx.x * 256 + threadIdx.x;
  if (e >= *pE) return;
  atomicAdd(&bcount[cluster[src[e]]], 1);
}

__global__ __launch_bounds__(1024) void k_scan(const int* __restrict__ in, int* __restrict__ out,
                                               int n, int* totalDst) {
  __shared__ int part[1024];
  int t = threadIdx.x;
  int chunk = (n + 1023) / 1024;
  int b = t * chunk, e = b + chunk;
  if (b > n) b = n;
  if (e > n) e = n;
  int s = 0;
  for (int i = b; i < e; i++) s += in[i];
  part[t] = s;
  __syncthreads();
  for (int off = 1; off < 1024; off <<= 1) {
    int v = (t >= off) ? part[t - off] : 0;
    __syncthreads();
    part[t] += v;
    __syncthreads();
  }
  int excl = (t == 0) ? 0 : part[t - 1];
  int total = part[1023];
  for (int i = b; i < e; i++) { out[i] = excl; excl += in[i]; }
  if (t == 0) {
    out[n] = total;
    if (totalDst) *totalDst = total;
  }
}

__global__ void k_bucket_scatter(const int* __restrict__ pE, const int* __restrict__ src,
                                 const int* __restrict__ dst, const int* __restrict__ cluster,
                                 const int* __restrict__ boffs, int* __restrict__ bcursor,
                                 int* __restrict__ bucket) {
  int e = blockIdx.x * 256 + threadIdx.x;
  if (e >= *pE) return;
  int cs = cluster[src[e]], cd = cluster[dst[e]];
  int pos = boffs[cs] + atomicAdd(&bcursor[cs], 1);
  bucket[pos] = cd;
}

__global__ void k_sort_dedup(const int* __restrict__ boffs, int* __restrict__ bucket,
                             int* __restrict__ ucount) {
  int v = blockIdx.x * 256 + threadIdx.x;
  if (v >= NN) return;
  int b = boffs[v], e = boffs[v + 1];
  for (int i = b + 1; i < e; i++) {
    int key = bucket[i];
    int j = i - 1;
    while (j >= b && bucket[j] > key) { bucket[j + 1] = bucket[j]; j--; }
    bucket[j + 1] = key;
  }
  int u = 0, prev = -2147483648;
  for (int i = b; i < e; i++) {
    int x = bucket[i];
    if (x != prev) { bucket[b + u] = x; u++; prev = x; }
  }
  ucount[v] = u;
}

__global__ void k_emit(const int* __restrict__ boffs, const int* __restrict__ bucket,
                       const int* __restrict__ bucount, const int* __restrict__ bnoffs,
                       int* __restrict__ srcO, int* __restrict__ dstO) {
  int v = blockIdx.x * 256 + threadIdx.x;
  if (v >= NN) return;
  int u = bucount[v], b = boffs[v], o = bnoffs[v];
  for (int i = 0; i < u; i++) { srcO[o + i] = v; dstO[o + i] = bucket[b + i]; }
}

// ---------------- readout ----------------
__global__ void k_graph_pool(const int* __restrict__ nvb, const int* __restrict__ batch,
                             const float* __restrict__ x, float* __restrict__ gsum,
                             float* __restrict__ gcnt) {
  int t = blockIdx.x * 256 + threadIdx.x;
  int n = t >> 2;
  if (n >= NN) return;
  if (!nvb[n]) return;
  int sub = t & 3;
  int g = batch[n];
  const float* xr = x + (size_t)n * HID + sub * 32;
  float* o = gsum + (size_t)g * HID + sub * 32;
#pragma unroll
  for (int i = 0; i < 8; i++) {
    float4 v = *(const float4*)(xr + i * 4);
    atomicAdd(o + i * 4 + 0, v.x); atomicAdd(o + i * 4 + 1, v.y);
    atomicAdd(o + i * 4 + 2, v.z); atomicAdd(o + i * 4 + 3, v.w);
  }
  if (sub == 0) atomicAdd(&gcnt[g], 1.0f);
}

__global__ __launch_bounds__(128) void k_head1(const float* __restrict__ gsum,
                                               const float* __restrict__ gcnt,
                                               const float* __restrict__ Wf1,
                                               const float* __restrict__ bf1,
                                               float* __restrict__ hfc) {
  int g = blockIdx.x;
  int j = threadIdx.x;
  __shared__ float p[HID];
  float c = fmaxf(gcnt[g], 1.f);
  p[j] = gsum[g * HID + j] / c;
  __syncthreads();
  float s = bf1[j];
  const float* w = Wf1 + (size_t)j * HID;
  for (int k = 0; k < HID; k++) s += p[k] * w[k];
  hfc[g * HID + j] = fmaxf(s, 0.f);
}

__global__ void k_head2(const float* __restrict__ hfc, const float* __restrict__ Wf2,
                        const float* __restrict__ bf2, float* __restrict__ out) {
  int g = blockIdx.x;
  int t = threadIdx.x;
  __shared__ float lg[NC];
  if (t < NC) {
    float s = bf2[t];
    const float* w = Wf2 + (size_t)t * HID;
    const float* h = hfc + (size_t)g * HID;
    for (int k = 0; k < HID; k++) s += h[k] * w[k];
    lg[t] = s;
  }
  __syncthreads();
  if (t == 0) {
    float m = lg[0];
    for (int c = 1; c < NC; c++) m = fmaxf(m, lg[c]);
    float se = 0.f;
    for (int c = 0; c < NC; c++) se += expf(lg[c] - m);
    float lse = m + logf(se);
    for (int c = 0; c < NC; c++) out[g * NC + c] = lg[c] - lse;
  }
}

extern "C" void kernel_launch(void* const* d_in, const int* in_sizes, int n_in,
                              void* d_out, int out_size, void* d_ws, size_t ws_size,
                              hipStream_t stream) {
  const float* x0 = (const float*)d_in[0];
  const int* ei = (const int*)d_in[1];
  const int* batch = (const int*)d_in[2];
  const float* Wl = (const float*)d_in[3];
  const float* bl = (const float*)d_in[4];
  const float* Wr = (const float*)d_in[5];
  const float* gamma = (const float*)d_in[6];
  const float* beta = (const float*)d_in[7];
  const float* Wlin = (const float*)d_in[8];
  const float* blin = (const float*)d_in[9];
  const float* Wp = (const float*)d_in[10];
  const float* bp = (const float*)d_in[11];
  const float* Wf1 = (const float*)d_in[12];
  const float* bf1 = (const float*)d_in[13];
  const float* Wf2 = (const float*)d_in[14];
  const float* bf2 = (const float*)d_in[15];
  float* out = (float*)d_out;

  const int NH = NN * HID;
  size_t off = 0;
  char* base = (char*)d_ws;
  auto carve = [&](size_t bytes) -> char* {
    char* p = base + off;
    off += (bytes + 255) & ~(size_t)255;
    return p;
  };
  float* xa = (float*)carve((size_t)NH * 4);
  float* xb = (float*)carve((size_t)NH * 4);
  float* xc = (float*)carve((size_t)NH * 4);
  float* xd = (float*)carve((size_t)NH * 4);
  int* srcA = (int*)carve((size_t)NE * 4);
  int* dstA = (int*)carve((size_t)NE * 4);
  int* srcB = (int*)carve((size_t)NE * 4);
  int* dstB = (int*)carve((size_t)NE * 4);
  float* escore = (float*)carve((size_t)NE * 4);
  int* eactive = (int*)carve((size_t)NE * 4);
  int* ebucket = (int*)carve((size_t)NE * 4);
  int* eids = (int*)carve((size_t)NE * 4);
  u64* ntop = (u64*)carve((size_t)NN * 8);
  float* npx1 = (float*)carve((size_t)NN * 4);
  float* npx2 = (float*)carve((size_t)NN * 4);
  int* ncluster = (int*)carve((size_t)NN * 4);
  int* nchosen = (int*)carve((size_t)NN * 4);
  int* nmatched = (int*)carve((size_t)NN * 4);
  int* nvb = (int*)carve((size_t)NN * 4);
  int* b3 = (int*)carve((size_t)3 * NN * 4);
  int* bcount = b3;
  int* bcursor = b3 + NN;
  int* bucount = b3 + 2 * NN;
  int* boffs = (int*)carve((size_t)(NN + 1) * 4);
  int* bnoffs = (int*)carve((size_t)(NN + 1) * 4);
  int* csroff = (int*)carve((size_t)(NN + 1) * 4);
  double* bnsum = (double*)carve((size_t)2 * HID * 8);
  float* gbuf = (float*)carve((size_t)(NG * HID + NG) * 4);
  float* gsum = gbuf;
  float* gcnt = gbuf + NG * HID;
  float* ghfc = (float*)carve((size_t)NG * HID * 4);
  int* scal = (int*)carve(64 * 4);
  int* progress = (int*)carve(MROUNDS * 4);
  (void)ws_size; (void)n_in; (void)in_sizes; (void)out_size;

  int* pE = scal;       // E_cur
  int* pcnt = scal + 1; // valid node count

  hipMemcpyAsync(xa, x0, (size_t)NH * 4, hipMemcpyDeviceToDevice, stream);
  k_init<<<1875, 256, 0, stream>>>(ei, srcA, dstA, nvb, scal);

  int* srcC = srcA; int* dstC = dstA; int* srcN = srcB; int* dstN = dstB;
  float* xcur = xa;
  float* xtmp = xd;

  auto sage = [&](const float* xin, float* xout, int L) {
    k_sage_gather<<<3750, 256, 0, stream>>>(csroff, eids, srcC, xin, xtmp);
    gemm_dual<<<469, 256, 0, stream>>>(xtmp, Wl + (size_t)L * HID * HID, xin,
                                       Wr + (size_t)L * HID * HID, bl + (size_t)L * HID,
                                       xout, NN, HID, 1);
    hipMemsetAsync(bnsum, 0, (size_t)2 * HID * 8, stream);
    k_bn_stats<<<235, 128, 0, stream>>>(xout, nvb, bnsum);
    k_bn_apply<<<15000, 256, 0, stream>>>(xout, bnsum, pcnt, gamma + (size_t)L * HID,
                                          beta + (size_t)L * HID);
  };

  for (int b = 0; b < 3; b++) {
    hipMemsetAsync(pcnt, 0, 4, stream);
    k_count_valid<<<118, 256, 0, stream>>>(nvb, pcnt);

    // CSR by dst (shared by both SAGE layers and edge softmax)
    hipMemsetAsync(b3, 0, (size_t)2 * NN * 4, stream);
    k_deg_count<<<1875, 256, 0, stream>>>(pE, dstC, bcount);
    k_scan<<<1, 1024, 0, stream>>>(bcount, csroff, NN, (int*)nullptr);
    k_csr_scatter<<<1875, 256, 0, stream>>>(pE, dstC, csroff, bcursor, eids);

    sage(xcur, xb, 2 * b);
    sage(xb, xc, 2 * b + 1);
    gemm_dual<<<469, 256, 0, stream>>>(xc, Wlin + (size_t)b * HID * 2 * HID, xb,
                                       Wlin + (size_t)b * HID * 2 * HID + HID,
                                       blin + (size_t)b * HID, xcur, NN, 2 * HID, 0);

    // ----- edge pooling -----
    k_node_proj<<<118, 256, 0, stream>>>(xcur, Wp + (size_t)b * 2 * HID, npx1, npx2);
    k_pool_init<<<118, 256, 0, stream>>>(nvb, nmatched, ncluster, nchosen, progress, ntop);
    k_edge_softmax<<<118, 256, 0, stream>>>(csroff, eids, srcC, npx1, npx2, bp + b,
                                            escore, eactive);
    for (int r = 0; r < MROUNDS; r++) {
      k_match_a<<<512, 256, 0, stream>>>(r, pE, srcC, dstC, escore, eactive, nmatched, ntop, progress);
      k_match_b<<<512, 256, 0, stream>>>(r, pE, srcC, dstC, escore, eactive, nmatched, ncluster,
                                         nchosen, ntop, progress);
    }
    k_new_x<<<3750, 256, 0, stream>>>(ncluster, nchosen, srcC, dstC, escore, xcur, xtmp);
    k_nvb_update<<<118, 256, 0, stream>>>(nvb, ncluster);

    hipMemsetAsync(b3, 0, (size_t)3 * NN * 4, stream);
    k_bucket_count<<<1875, 256, 0, stream>>>(pE, srcC, ncluster, bcount);
    k_scan<<<1, 1024, 0, stream>>>(bcount, boffs, NN, (int*)nullptr);
    k_bucket_scatter<<<1875, 256, 0, stream>>>(pE, srcC, dstC, ncluster, boffs, bcursor, ebucket);
    k_sort_dedup<<<118, 256, 0, stream>>>(boffs, ebucket, bucount);
    k_scan<<<1, 1024, 0, stream>>>(bucount, bnoffs, NN, pE);
    k_emit<<<118, 256, 0, stream>>>(boffs, ebucket, bucount, bnoffs, srcN, dstN);

    { int* t = srcC; srcC = srcN; srcN = t; t = dstC; dstC = dstN; dstN = t; }
    { float* t = xcur; xcur = xtmp; xtmp = t; }
  }

  hipMemsetAsync(gbuf, 0, (size_t)(NG * HID + NG) * 4, stream);
  k_graph_pool<<<469, 256, 0, stream>>>(nvb, batch, xcur, gsum, gcnt);
  k_head1<<<NG, 128, 0, stream>>>(gsum, gcnt, Wf1, bf1, ghfc);
  k_head2<<<NG, 32, 0, stream>>>(ghfc, Wf2, bf2, out);
}